// Round 7
// baseline (408.495 us; speedup 1.0000x reference)
//
#include <hip/hip_runtime.h>
#include <hip/hip_bf16.h>
#include <math.h>

typedef __hip_bfloat16 bf16;
using short8 = __attribute__((ext_vector_type(8))) short;
using f32x4  = __attribute__((ext_vector_type(4))) float;

__device__ __forceinline__ bf16 f2b(float v){ return __float2bfloat16(v); }
__device__ __forceinline__ float gelu_exact(float v){ return 0.5f * v * (1.f + erff(v * 0.70710678118654752f)); }

// ============================================================================
// Weight prep: fp32 weights -> bf16 fragment layout for mfma_f32_16x16x32_bf16.
// Fragment f=(nt,kt): lane l, elem i holds W[nt*16+(l&15)][kt*32+8*(l>>4)+i],
// at dst[f*512 + l*8 + i]. Bits serve as B-frags and A-frags interchangeably.
// ws layout (bf16): qkv @0 (54), proj @54*512 (18), fc1 @72*512 (72),
// fc2 @144*512 (72). Total 216 KiB.
// ============================================================================
__global__ __launch_bounds__(256)
void prep_weights(const float* __restrict__ qkv_w, const float* __restrict__ proj_w,
                  const float* __restrict__ fc1_w, const float* __restrict__ fc2_w,
                  bf16* __restrict__ ws)
{
    const int t = blockIdx.x * 256 + threadIdx.x;
    const int f = t >> 6;
    const int lane = t & 63;
    const float* W; int KT, fr; bf16* dst;
    if (f < 54)       { W = qkv_w;  KT = 3;  fr = f;       dst = ws; }
    else if (f < 72)  { W = proj_w; KT = 3;  fr = f - 54;  dst = ws + 54*512; }
    else if (f < 144) { W = fc1_w;  KT = 3;  fr = f - 72;  dst = ws + 72*512; }
    else              { W = fc2_w;  KT = 12; fr = f - 144; dst = ws + 144*512; }
    const int nt = fr / KT, kt = fr % KT;
    const int Kin = KT * 32;
    const float* src = W + (nt*16 + (lane & 15))*Kin + kt*32 + 8*(lane >> 4);
    const float4 s0 = *(const float4*)src;
    const float4 s1 = *(const float4*)(src + 4);
    union { bf16 h[8]; short8 v; } u;
    u.h[0]=f2b(s0.x); u.h[1]=f2b(s0.y); u.h[2]=f2b(s0.z); u.h[3]=f2b(s0.w);
    u.h[4]=f2b(s1.x); u.h[5]=f2b(s1.y); u.h[6]=f2b(s1.z); u.h[7]=f2b(s1.w);
    *(short8*)(dst + fr*512 + lane*8) = u.v;
}

// ============================================================================
// FUSED kernel v3 (= v2 structure, spill fix). Block = 1 window, 4 waves.
// R6 lesson: __launch_bounds__(256,4) capped VGPR at 64 -> ~150 MB of scratch
// spill traffic (WRITE_SIZE 98->174 MB). (256,3) compiles at ~84-110 VGPR with
// zero spill (R5-proven); LDS 37376 B still admits 4 blocks/CU, and VGPR<=128
// keeps the 4-waves/EU hardware occupancy.
// LDS pool aliasing:
//   attn: q_s@0 | k_s@5120 | vt_s@10240 | p_s@14848 | ao_s@24064 (end 37376)
//   mlp : ln2s == ao_s (wave-local rows); hid@0 [64][200]=25600 B (barrier
//         after FC1 A-frag loads protects the overlap).
// ============================================================================
__global__ __launch_bounds__(256, 3)
void swin_fused(const float* __restrict__ x,
                const float* __restrict__ ln1_w, const float* __restrict__ ln1_b,
                const float* __restrict__ qkv_b, const float* __restrict__ proj_b,
                const float* __restrict__ ln2_w, const float* __restrict__ ln2_b,
                const float* __restrict__ fc1_b, const float* __restrict__ fc2_b,
                const bf16* __restrict__ wsf,
                float* __restrict__ out)
{
    __shared__ __align__(16) char pool[37376];
    bf16 (*q_s)[40]   = (bf16(*)[40])(pool + 0);       //  5120 B
    bf16 (*k_s)[40]   = (bf16(*)[40])(pool + 5120);    //  5120 B
    bf16 (*vt_s)[72]  = (bf16(*)[72])(pool + 10240);   //  4608 B
    bf16 (*p_s)[72]   = (bf16(*)[72])(pool + 14848);   //  9216 B
    bf16 (*ao_s)[104] = (bf16(*)[104])(pool + 24064);  // 13312 B (end 37376)
    bf16 (*ln2s)[104] = ao_s;                          // alias (wave-local rows)
    bf16 (*hid)[200]  = (bf16(*)[200])(pool + 0);      // 25600 B

    const int tid = threadIdx.x;
    const int win = blockIdx.x;
    const int b  = win >> 11;
    const int wd = (win >> 8) & 7;
    const int wh = (win >> 4) & 15;
    const int ww = win & 15;

    const int w    = tid >> 6;
    const int lane = tid & 63;
    const int lc   = lane & 15;
    const int lr   = lane >> 4;
    const int m0   = w * 16;
    const int tokr = m0 + lr*4;
    const float scale = 0.17677669529663688f;

    // inline shifted-window gather offset for token n of this window
    auto tok_offset = [&](int n) -> int {
        const int df = (wd*4 + (n >> 4)       + 2) & 31;
        const int hf = (wh*4 + ((n >> 2) & 3) + 2) & 63;
        const int wf = (ww*4 + (n & 3)        + 2) & 63;
        return (((b*32 + df)*64 + hf)*64 + wf) * 96;
    };
    const int myTok = tok_offset(m0 + lc);   // A-frag token
    int toks[4];
    #pragma unroll
    for (int r = 0; r < 4; r++) toks[r] = tok_offset(tokr + r);

    // ---- LN1 directly into A-frag registers ----
    short8 lnA[3];
    {
        float v[3][8];
        float s = 0.f, ss = 0.f;
        #pragma unroll
        for (int kt = 0; kt < 3; kt++) {
            const float4 a = *(const float4*)(x + myTok + kt*32 + 8*lr);
            const float4 c = *(const float4*)(x + myTok + kt*32 + 8*lr + 4);
            v[kt][0]=a.x; v[kt][1]=a.y; v[kt][2]=a.z; v[kt][3]=a.w;
            v[kt][4]=c.x; v[kt][5]=c.y; v[kt][6]=c.z; v[kt][7]=c.w;
            #pragma unroll
            for (int i = 0; i < 8; i++) { s += v[kt][i]; ss += v[kt][i]*v[kt][i]; }
        }
        s += __shfl_xor(s, 16); ss += __shfl_xor(ss, 16);
        s += __shfl_xor(s, 32); ss += __shfl_xor(ss, 32);
        const float mean = s * (1.f/96.f);
        const float var  = ss * (1.f/96.f) - mean*mean;
        const float inv  = rsqrtf(var + 1e-5f);
        #pragma unroll
        for (int kt = 0; kt < 3; kt++) {
            const float4 w0 = *(const float4*)(ln1_w + kt*32 + 8*lr);
            const float4 w1 = *(const float4*)(ln1_w + kt*32 + 8*lr + 4);
            const float4 b0 = *(const float4*)(ln1_b + kt*32 + 8*lr);
            const float4 b1 = *(const float4*)(ln1_b + kt*32 + 8*lr + 4);
            const float wv[8] = {w0.x,w0.y,w0.z,w0.w,w1.x,w1.y,w1.z,w1.w};
            const float bv[8] = {b0.x,b0.y,b0.z,b0.w,b1.x,b1.y,b1.z,b1.w};
            union { bf16 h[8]; short8 v8; } u;
            #pragma unroll
            for (int i = 0; i < 8; i++)
                u.h[i] = f2b((v[kt][i] - mean) * inv * wv[i] + bv[i]);
            lnA[kt] = u.v8;
        }
    }

    // ================= attention (validated structure) =================
    for (int h = 0; h < 3; h++) {
        #pragma unroll
        for (int nt2 = 0; nt2 < 2; nt2++) {
            const int dd = nt2*16 + lc;
            {
                f32x4 acc = {0.f,0.f,0.f,0.f};
                #pragma unroll
                for (int kt = 0; kt < 3; kt++)
                    acc = __builtin_amdgcn_mfma_f32_16x16x32_bf16(
                        lnA[kt], *(const short8*)(wsf + ((2*h+nt2)*3+kt)*512 + lane*8), acc, 0,0,0);
                const float bias = qkv_b[h*32 + dd];
                #pragma unroll
                for (int r = 0; r < 4; r++)
                    q_s[tokr + r][dd] = f2b((acc[r] + bias) * scale);
            }
            {
                f32x4 acc = {0.f,0.f,0.f,0.f};
                #pragma unroll
                for (int kt = 0; kt < 3; kt++)
                    acc = __builtin_amdgcn_mfma_f32_16x16x32_bf16(
                        lnA[kt], *(const short8*)(wsf + ((6+2*h+nt2)*3+kt)*512 + lane*8), acc, 0,0,0);
                const float bias = qkv_b[96 + h*32 + dd];
                #pragma unroll
                for (int r = 0; r < 4; r++)
                    k_s[tokr + r][dd] = f2b(acc[r] + bias);
            }
            {
                f32x4 acc = {0.f,0.f,0.f,0.f};
                #pragma unroll
                for (int kt = 0; kt < 3; kt++)
                    acc = __builtin_amdgcn_mfma_f32_16x16x32_bf16(
                        *(const short8*)(wsf + ((12+2*h+nt2)*3+kt)*512 + lane*8), lnA[kt], acc, 0,0,0);
                #pragma unroll
                for (int r = 0; r < 4; r++) {
                    const int dl = nt2*16 + lr*4 + r;
                    vt_s[dl][m0 + lc] = f2b(acc[r] + qkv_b[192 + h*32 + dl]);
                }
            }
        }
        __syncthreads();

        {
            const short8 qf = *(const short8*)&q_s[m0 + lc][8*lr];
            f32x4 sacc[4];
            #pragma unroll
            for (int nt = 0; nt < 4; nt++) {
                f32x4 z = {0.f,0.f,0.f,0.f};
                sacc[nt] = __builtin_amdgcn_mfma_f32_16x16x32_bf16(
                    qf, *(const short8*)&k_s[nt*16 + lc][8*lr], z, 0,0,0);
            }
            #pragma unroll
            for (int r = 0; r < 4; r++) {
                float mx = fmaxf(fmaxf(sacc[0][r], sacc[1][r]), fmaxf(sacc[2][r], sacc[3][r]));
                mx = fmaxf(mx, __shfl_xor(mx, 1));
                mx = fmaxf(mx, __shfl_xor(mx, 2));
                mx = fmaxf(mx, __shfl_xor(mx, 4));
                mx = fmaxf(mx, __shfl_xor(mx, 8));
                float e[4], sum = 0.f;
                #pragma unroll
                for (int nt = 0; nt < 4; nt++) { e[nt] = __expf(sacc[nt][r] - mx); sum += e[nt]; }
                sum += __shfl_xor(sum, 1);
                sum += __shfl_xor(sum, 2);
                sum += __shfl_xor(sum, 4);
                sum += __shfl_xor(sum, 8);
                const float rs = 1.f / sum;
                #pragma unroll
                for (int nt = 0; nt < 4; nt++)
                    p_s[tokr + r][nt*16 + lc] = f2b(e[nt] * rs);
            }
        }

        {
            short8 pf[2];
            #pragma unroll
            for (int kt = 0; kt < 2; kt++)
                pf[kt] = *(const short8*)&p_s[m0 + lc][kt*32 + 8*lr];
            #pragma unroll
            for (int nt = 0; nt < 2; nt++) {
                f32x4 acc = {0.f,0.f,0.f,0.f};
                #pragma unroll
                for (int kt = 0; kt < 2; kt++)
                    acc = __builtin_amdgcn_mfma_f32_16x16x32_bf16(
                        pf[kt], *(const short8*)&vt_s[nt*16 + lc][kt*32 + 8*lr], acc, 0,0,0);
                #pragma unroll
                for (int r = 0; r < 4; r++)
                    ao_s[tokr + r][h*32 + nt*16 + lc] = f2b(acc[r]);
            }
        }
        __syncthreads();
    }

    // ---- proj + bias + residual -> x2 in registers (C-layout) ----
    f32x4 xv[6];
    {
        short8 af[3];
        #pragma unroll
        for (int kt = 0; kt < 3; kt++)
            af[kt] = *(const short8*)&ao_s[m0 + lc][kt*32 + 8*lr];
        const bf16* pw = wsf + 54*512;
        #pragma unroll
        for (int nt = 0; nt < 6; nt++) {
            f32x4 acc = {0.f,0.f,0.f,0.f};
            #pragma unroll
            for (int kt = 0; kt < 3; kt++)
                acc = __builtin_amdgcn_mfma_f32_16x16x32_bf16(
                    af[kt], *(const short8*)(pw + (nt*3+kt)*512 + lane*8), acc, 0,0,0);
            const int c = nt*16 + lc;
            const float bias = proj_b[c];
            #pragma unroll
            for (int r = 0; r < 4; r++)
                xv[nt][r] = x[toks[r] + c] + acc[r] + bias;
        }
    }

    // ---- LN2 in registers -> ln2s (alias ao_s; wave-local rows) ----
    {
        float wl[6], bl[6];
        #pragma unroll
        for (int nt = 0; nt < 6; nt++) { wl[nt] = ln2_w[nt*16 + lc]; bl[nt] = ln2_b[nt*16 + lc]; }
        #pragma unroll
        for (int r = 0; r < 4; r++) {
            float s = 0.f, ss = 0.f;
            #pragma unroll
            for (int nt = 0; nt < 6; nt++) { const float v = xv[nt][r]; s += v; ss += v*v; }
            s += __shfl_xor(s, 1); ss += __shfl_xor(ss, 1);
            s += __shfl_xor(s, 2); ss += __shfl_xor(ss, 2);
            s += __shfl_xor(s, 4); ss += __shfl_xor(ss, 4);
            s += __shfl_xor(s, 8); ss += __shfl_xor(ss, 8);
            const float mean = s * (1.f/96.f);
            const float var  = ss * (1.f/96.f) - mean*mean;
            const float inv  = rsqrtf(var + 1e-5f);
            #pragma unroll
            for (int nt = 0; nt < 6; nt++)
                ln2s[tokr + r][nt*16 + lc] = f2b((xv[nt][r] - mean) * inv * wl[nt] + bl[nt]);
        }
    }

    // FC1 A-frags, then barrier so hid may overwrite the ln2s-overlap region
    short8 afr[3];
    #pragma unroll
    for (int kt = 0; kt < 3; kt++)
        afr[kt] = *(const short8*)&ln2s[m0 + lc][kt*32 + 8*lr];
    __syncthreads();

    // ---- MLP: 2 chunks of 192 hidden cols; hid rows are wave-private ----
    const bf16* w1f = wsf + 72*512;
    const bf16* w2f = wsf + 144*512;
    f32x4 acc2[6];
    #pragma unroll
    for (int nt = 0; nt < 6; nt++) acc2[nt] = (f32x4){0.f,0.f,0.f,0.f};

    #pragma unroll
    for (int c = 0; c < 2; c++) {
        // FC1 + GELU for local n-tiles 0..11 (groups of 2, frags preloaded)
        #pragma unroll
        for (int g = 0; g < 6; g++) {
            short8 bfB[2][3];
            #pragma unroll
            for (int q = 0; q < 2; q++) {
                const int nt = c*12 + g*2 + q;
                #pragma unroll
                for (int kt = 0; kt < 3; kt++)
                    bfB[q][kt] = *(const short8*)(w1f + (nt*3 + kt)*512 + lane*8);
            }
            f32x4 a0 = {0.f,0.f,0.f,0.f}, a1 = {0.f,0.f,0.f,0.f};
            #pragma unroll
            for (int kt = 0; kt < 3; kt++) {
                a0 = __builtin_amdgcn_mfma_f32_16x16x32_bf16(afr[kt], bfB[0][kt], a0, 0,0,0);
                a1 = __builtin_amdgcn_mfma_f32_16x16x32_bf16(afr[kt], bfB[1][kt], a1, 0,0,0);
            }
            const int ntl = g*2;
            const int j0  = (c*12 + ntl)*16 + lc;
            const float bi0 = fc1_b[j0], bi1 = fc1_b[j0 + 16];
            #pragma unroll
            for (int r = 0; r < 4; r++) {
                hid[tokr + r][ntl*16 + lc]      = f2b(gelu_exact(a0[r] + bi0));
                hid[tokr + r][(ntl+1)*16 + lc]  = f2b(gelu_exact(a1[r] + bi1));
            }
            __syncthreads();   // convergence: keep 4 waves on the same frags (L1)
        }

        // FC2 partial: A-frags from own hid rows, 6 nt x 6 kt
        short8 af2[6];
        #pragma unroll
        for (int kt = 0; kt < 6; kt++)
            af2[kt] = *(const short8*)&hid[m0 + lc][kt*32 + 8*lr];
        #pragma unroll
        for (int nt = 0; nt < 6; nt++) {
            #pragma unroll
            for (int kt = 0; kt < 6; kt++)
                acc2[nt] = __builtin_amdgcn_mfma_f32_16x16x32_bf16(
                    af2[kt], *(const short8*)(w2f + (nt*12 + c*6 + kt)*512 + lane*8), acc2[nt], 0,0,0);
        }
        __syncthreads();       // convergence before next chunk's FC1
    }

    // ---- FC2 bias + residual -> single global write ----
    #pragma unroll
    for (int nt = 0; nt < 6; nt++) {
        const int c = nt*16 + lc;
        const float bias = fc2_b[c];
        #pragma unroll
        for (int r = 0; r < 4; r++)
            out[toks[r] + c] = xv[nt][r] + acc2[nt][r] + bias;
    }
}

extern "C" void kernel_launch(void* const* d_in, const int* in_sizes, int n_in,
                              void* d_out, int out_size, void* d_ws, size_t ws_size,
                              hipStream_t stream)
{
    const float* x      = (const float*)d_in[0];
    const float* ln1_w  = (const float*)d_in[1];
    const float* ln1_b  = (const float*)d_in[2];
    const float* qkv_w  = (const float*)d_in[3];
    const float* qkv_b  = (const float*)d_in[4];
    const float* proj_w = (const float*)d_in[5];
    const float* proj_b = (const float*)d_in[6];
    const float* ln2_w  = (const float*)d_in[7];
    const float* ln2_b  = (const float*)d_in[8];
    const float* fc1_w  = (const float*)d_in[9];
    const float* fc1_b  = (const float*)d_in[10];
    const float* fc2_w  = (const float*)d_in[11];
    const float* fc2_b  = (const float*)d_in[12];
    float* out = (float*)d_out;
    bf16* wsf  = (bf16*)d_ws;   // 216 KiB

    prep_weights<<<54, 256, 0, stream>>>(qkv_w, proj_w, fc1_w, fc2_w, wsf);
    swin_fused<<<4096, 256, 0, stream>>>(x, ln1_w, ln1_b, qkv_b, proj_b,
                                         ln2_w, ln2_b, fc1_b, fc2_b, wsf, out);
}

// Round 8
// 339.028 us; speedup vs baseline: 1.2049x; 1.2049x over previous
//
#include <hip/hip_runtime.h>
#include <hip/hip_bf16.h>
#include <math.h>

typedef __hip_bfloat16 bf16;
using short8 = __attribute__((ext_vector_type(8))) short;
using f32x4  = __attribute__((ext_vector_type(4))) float;

__device__ __forceinline__ bf16 f2b(float v){ return __float2bfloat16(v); }
__device__ __forceinline__ float gelu_exact(float v){ return 0.5f * v * (1.f + erff(v * 0.70710678118654752f)); }

// ============================================================================
// Weight prep: fp32 weights -> bf16 fragment layout for mfma_f32_16x16x32_bf16.
// Fragment f=(nt,kt): lane l, elem i holds W[nt*16+(l&15)][kt*32+8*(l>>4)+i],
// at dst[f*512 + l*8 + i]. Bits serve as B-frags and A-frags interchangeably.
// ws layout (bf16): qkv @0 (54), proj @54*512 (18), fc1 @72*512 (72),
// fc2 @144*512 (72). Total 216 KiB.
// ============================================================================
__global__ __launch_bounds__(256)
void prep_weights(const float* __restrict__ qkv_w, const float* __restrict__ proj_w,
                  const float* __restrict__ fc1_w, const float* __restrict__ fc2_w,
                  bf16* __restrict__ ws)
{
    const int t = blockIdx.x * 256 + threadIdx.x;
    const int f = t >> 6;
    const int lane = t & 63;
    const float* W; int KT, fr; bf16* dst;
    if (f < 54)       { W = qkv_w;  KT = 3;  fr = f;       dst = ws; }
    else if (f < 72)  { W = proj_w; KT = 3;  fr = f - 54;  dst = ws + 54*512; }
    else if (f < 144) { W = fc1_w;  KT = 3;  fr = f - 72;  dst = ws + 72*512; }
    else              { W = fc2_w;  KT = 12; fr = f - 144; dst = ws + 144*512; }
    const int nt = fr / KT, kt = fr % KT;
    const int Kin = KT * 32;
    const float* src = W + (nt*16 + (lane & 15))*Kin + kt*32 + 8*(lane >> 4);
    const float4 s0 = *(const float4*)src;
    const float4 s1 = *(const float4*)(src + 4);
    union { bf16 h[8]; short8 v; } u;
    u.h[0]=f2b(s0.x); u.h[1]=f2b(s0.y); u.h[2]=f2b(s0.z); u.h[3]=f2b(s0.w);
    u.h[4]=f2b(s1.x); u.h[5]=f2b(s1.y); u.h[6]=f2b(s1.z); u.h[7]=f2b(s1.w);
    *(short8*)(dst + fr*512 + lane*8) = u.v;
}

// ============================================================================
// FUSED kernel v4: register-diet for 4 blocks/CU WITHOUT spill.
// R6: (256,4) -> 4 blocks/CU, dispatch 252us, but 64-VGPR cap spilled (+150MB).
// R7: (256,3) -> no spill but VGPR+AGPR ~136 -> 3 waves/EU, occ 31.7%, 291us.
// v4: (a) xv folded into acc2 via MFMA C-operand (acc2 init = xv + fc2_b;
//     FC2 accumulates on top; out = acc2) -- kills 24 live regs through MLP;
//     (b) MLP convergence barriers dropped (R5 vs R7: perf-neutral; hid/ln2s
//     rows wave-private; only the ln2s/hid alias barrier is required).
// Peak live ~90 regs -> (256,4) (<=128 VGPR+AGPR) should compile spill-free.
// LDS pool aliasing:
//   attn: q_s@0 | k_s@5120 | vt_s@10240 | p_s@14848 | ao_s@24064 (end 37376)
//   mlp : ln2s == ao_s (wave-local rows); hid@0 [64][200]=25600 B (barrier
//         after FC1 A-frag loads protects the rows-60..63 overlap).
// ============================================================================
__global__ __launch_bounds__(256, 4)
void swin_fused(const float* __restrict__ x,
                const float* __restrict__ ln1_w, const float* __restrict__ ln1_b,
                const float* __restrict__ qkv_b, const float* __restrict__ proj_b,
                const float* __restrict__ ln2_w, const float* __restrict__ ln2_b,
                const float* __restrict__ fc1_b, const float* __restrict__ fc2_b,
                const bf16* __restrict__ wsf,
                float* __restrict__ out)
{
    __shared__ __align__(16) char pool[37376];
    bf16 (*q_s)[40]   = (bf16(*)[40])(pool + 0);       //  5120 B
    bf16 (*k_s)[40]   = (bf16(*)[40])(pool + 5120);    //  5120 B
    bf16 (*vt_s)[72]  = (bf16(*)[72])(pool + 10240);   //  4608 B
    bf16 (*p_s)[72]   = (bf16(*)[72])(pool + 14848);   //  9216 B
    bf16 (*ao_s)[104] = (bf16(*)[104])(pool + 24064);  // 13312 B (end 37376)
    bf16 (*ln2s)[104] = ao_s;                          // alias (wave-local rows)
    bf16 (*hid)[200]  = (bf16(*)[200])(pool + 0);      // 25600 B

    const int tid = threadIdx.x;
    const int win = blockIdx.x;
    const int b  = win >> 11;
    const int wd = (win >> 8) & 7;
    const int wh = (win >> 4) & 15;
    const int ww = win & 15;

    const int w    = tid >> 6;
    const int lane = tid & 63;
    const int lc   = lane & 15;
    const int lr   = lane >> 4;
    const int m0   = w * 16;
    const int tokr = m0 + lr*4;
    const float scale = 0.17677669529663688f;

    // inline shifted-window gather offset for token n of this window
    auto tok_offset = [&](int n) -> int {
        const int df = (wd*4 + (n >> 4)       + 2) & 31;
        const int hf = (wh*4 + ((n >> 2) & 3) + 2) & 63;
        const int wf = (ww*4 + (n & 3)        + 2) & 63;
        return (((b*32 + df)*64 + hf)*64 + wf) * 96;
    };
    const int myTok = tok_offset(m0 + lc);   // A-frag token
    int toks[4];
    #pragma unroll
    for (int r = 0; r < 4; r++) toks[r] = tok_offset(tokr + r);

    // ---- LN1 directly into A-frag registers ----
    short8 lnA[3];
    {
        float v[3][8];
        float s = 0.f, ss = 0.f;
        #pragma unroll
        for (int kt = 0; kt < 3; kt++) {
            const float4 a = *(const float4*)(x + myTok + kt*32 + 8*lr);
            const float4 c = *(const float4*)(x + myTok + kt*32 + 8*lr + 4);
            v[kt][0]=a.x; v[kt][1]=a.y; v[kt][2]=a.z; v[kt][3]=a.w;
            v[kt][4]=c.x; v[kt][5]=c.y; v[kt][6]=c.z; v[kt][7]=c.w;
            #pragma unroll
            for (int i = 0; i < 8; i++) { s += v[kt][i]; ss += v[kt][i]*v[kt][i]; }
        }
        s += __shfl_xor(s, 16); ss += __shfl_xor(ss, 16);
        s += __shfl_xor(s, 32); ss += __shfl_xor(ss, 32);
        const float mean = s * (1.f/96.f);
        const float var  = ss * (1.f/96.f) - mean*mean;
        const float inv  = rsqrtf(var + 1e-5f);
        #pragma unroll
        for (int kt = 0; kt < 3; kt++) {
            const float4 w0 = *(const float4*)(ln1_w + kt*32 + 8*lr);
            const float4 w1 = *(const float4*)(ln1_w + kt*32 + 8*lr + 4);
            const float4 b0 = *(const float4*)(ln1_b + kt*32 + 8*lr);
            const float4 b1 = *(const float4*)(ln1_b + kt*32 + 8*lr + 4);
            const float wv[8] = {w0.x,w0.y,w0.z,w0.w,w1.x,w1.y,w1.z,w1.w};
            const float bv[8] = {b0.x,b0.y,b0.z,b0.w,b1.x,b1.y,b1.z,b1.w};
            union { bf16 h[8]; short8 v8; } u;
            #pragma unroll
            for (int i = 0; i < 8; i++)
                u.h[i] = f2b((v[kt][i] - mean) * inv * wv[i] + bv[i]);
            lnA[kt] = u.v8;
        }
    }

    // ================= attention (validated structure) =================
    for (int h = 0; h < 3; h++) {
        #pragma unroll
        for (int nt2 = 0; nt2 < 2; nt2++) {
            const int dd = nt2*16 + lc;
            {
                f32x4 acc = {0.f,0.f,0.f,0.f};
                #pragma unroll
                for (int kt = 0; kt < 3; kt++)
                    acc = __builtin_amdgcn_mfma_f32_16x16x32_bf16(
                        lnA[kt], *(const short8*)(wsf + ((2*h+nt2)*3+kt)*512 + lane*8), acc, 0,0,0);
                const float bias = qkv_b[h*32 + dd];
                #pragma unroll
                for (int r = 0; r < 4; r++)
                    q_s[tokr + r][dd] = f2b((acc[r] + bias) * scale);
            }
            {
                f32x4 acc = {0.f,0.f,0.f,0.f};
                #pragma unroll
                for (int kt = 0; kt < 3; kt++)
                    acc = __builtin_amdgcn_mfma_f32_16x16x32_bf16(
                        lnA[kt], *(const short8*)(wsf + ((6+2*h+nt2)*3+kt)*512 + lane*8), acc, 0,0,0);
                const float bias = qkv_b[96 + h*32 + dd];
                #pragma unroll
                for (int r = 0; r < 4; r++)
                    k_s[tokr + r][dd] = f2b(acc[r] + bias);
            }
            {
                f32x4 acc = {0.f,0.f,0.f,0.f};
                #pragma unroll
                for (int kt = 0; kt < 3; kt++)
                    acc = __builtin_amdgcn_mfma_f32_16x16x32_bf16(
                        *(const short8*)(wsf + ((12+2*h+nt2)*3+kt)*512 + lane*8), lnA[kt], acc, 0,0,0);
                #pragma unroll
                for (int r = 0; r < 4; r++) {
                    const int dl = nt2*16 + lr*4 + r;
                    vt_s[dl][m0 + lc] = f2b(acc[r] + qkv_b[192 + h*32 + dl]);
                }
            }
        }
        __syncthreads();

        {
            const short8 qf = *(const short8*)&q_s[m0 + lc][8*lr];
            f32x4 sacc[4];
            #pragma unroll
            for (int nt = 0; nt < 4; nt++) {
                f32x4 z = {0.f,0.f,0.f,0.f};
                sacc[nt] = __builtin_amdgcn_mfma_f32_16x16x32_bf16(
                    qf, *(const short8*)&k_s[nt*16 + lc][8*lr], z, 0,0,0);
            }
            #pragma unroll
            for (int r = 0; r < 4; r++) {
                float mx = fmaxf(fmaxf(sacc[0][r], sacc[1][r]), fmaxf(sacc[2][r], sacc[3][r]));
                mx = fmaxf(mx, __shfl_xor(mx, 1));
                mx = fmaxf(mx, __shfl_xor(mx, 2));
                mx = fmaxf(mx, __shfl_xor(mx, 4));
                mx = fmaxf(mx, __shfl_xor(mx, 8));
                float e[4], sum = 0.f;
                #pragma unroll
                for (int nt = 0; nt < 4; nt++) { e[nt] = __expf(sacc[nt][r] - mx); sum += e[nt]; }
                sum += __shfl_xor(sum, 1);
                sum += __shfl_xor(sum, 2);
                sum += __shfl_xor(sum, 4);
                sum += __shfl_xor(sum, 8);
                const float rs = 1.f / sum;
                #pragma unroll
                for (int nt = 0; nt < 4; nt++)
                    p_s[tokr + r][nt*16 + lc] = f2b(e[nt] * rs);
            }
        }

        {
            short8 pf[2];
            #pragma unroll
            for (int kt = 0; kt < 2; kt++)
                pf[kt] = *(const short8*)&p_s[m0 + lc][kt*32 + 8*lr];
            #pragma unroll
            for (int nt = 0; nt < 2; nt++) {
                f32x4 acc = {0.f,0.f,0.f,0.f};
                #pragma unroll
                for (int kt = 0; kt < 2; kt++)
                    acc = __builtin_amdgcn_mfma_f32_16x16x32_bf16(
                        pf[kt], *(const short8*)&vt_s[nt*16 + lc][kt*32 + 8*lr], acc, 0,0,0);
                #pragma unroll
                for (int r = 0; r < 4; r++)
                    ao_s[tokr + r][h*32 + nt*16 + lc] = f2b(acc[r]);
            }
        }
        __syncthreads();
    }

    // ---- proj + bias + residual -> xv regs, immediately folded into acc2 ----
    f32x4 acc2[6];   // becomes FC2 accumulator: init = x + attn + proj_b ... + fc2_b
    {
        short8 af[3];
        #pragma unroll
        for (int kt = 0; kt < 3; kt++)
            af[kt] = *(const short8*)&ao_s[m0 + lc][kt*32 + 8*lr];
        const bf16* pw = wsf + 54*512;
        #pragma unroll
        for (int nt = 0; nt < 6; nt++) {
            f32x4 acc = {0.f,0.f,0.f,0.f};
            #pragma unroll
            for (int kt = 0; kt < 3; kt++)
                acc = __builtin_amdgcn_mfma_f32_16x16x32_bf16(
                    af[kt], *(const short8*)(pw + (nt*3+kt)*512 + lane*8), acc, 0,0,0);
            const int c = nt*16 + lc;
            const float bias = proj_b[c];
            #pragma unroll
            for (int r = 0; r < 4; r++)
                acc2[nt][r] = x[toks[r] + c] + acc[r] + bias;   // = xv
        }
    }

    // ---- LN2 in registers (stats over acc2 == xv) -> ln2s (alias ao_s) ----
    {
        #pragma unroll
        for (int r = 0; r < 4; r++) {
            float s = 0.f, ss = 0.f;
            #pragma unroll
            for (int nt = 0; nt < 6; nt++) { const float v = acc2[nt][r]; s += v; ss += v*v; }
            s += __shfl_xor(s, 1); ss += __shfl_xor(ss, 1);
            s += __shfl_xor(s, 2); ss += __shfl_xor(ss, 2);
            s += __shfl_xor(s, 4); ss += __shfl_xor(ss, 4);
            s += __shfl_xor(s, 8); ss += __shfl_xor(ss, 8);
            const float mean = s * (1.f/96.f);
            const float var  = ss * (1.f/96.f) - mean*mean;
            const float inv  = rsqrtf(var + 1e-5f);
            #pragma unroll
            for (int nt = 0; nt < 6; nt++) {
                const int c = nt*16 + lc;
                ln2s[tokr + r][c] = f2b((acc2[nt][r] - mean) * inv * ln2_w[c] + ln2_b[c]);
            }
        }
    }

    // fold fc2 bias into the accumulator now (xv dies; acc2 is the only copy)
    #pragma unroll
    for (int nt = 0; nt < 6; nt++) {
        const float bias = fc2_b[nt*16 + lc];
        #pragma unroll
        for (int r = 0; r < 4; r++) acc2[nt][r] += bias;
    }

    // FC1 A-frags, then barrier: hid rows 60..63 overlap ln2s rows 0..7
    short8 afr[3];
    #pragma unroll
    for (int kt = 0; kt < 3; kt++)
        afr[kt] = *(const short8*)&ln2s[m0 + lc][kt*32 + 8*lr];
    __syncthreads();

    // ---- MLP: 2 chunks of 192 hidden cols; hid rows wave-private, no barriers ----
    const bf16* w1f = wsf + 72*512;
    const bf16* w2f = wsf + 144*512;

    #pragma unroll
    for (int c = 0; c < 2; c++) {
        // FC1 + GELU for local n-tiles 0..11 (groups of 2, frags preloaded)
        #pragma unroll
        for (int g = 0; g < 6; g++) {
            short8 bfB[2][3];
            #pragma unroll
            for (int q = 0; q < 2; q++) {
                const int nt = c*12 + g*2 + q;
                #pragma unroll
                for (int kt = 0; kt < 3; kt++)
                    bfB[q][kt] = *(const short8*)(w1f + (nt*3 + kt)*512 + lane*8);
            }
            f32x4 a0 = {0.f,0.f,0.f,0.f}, a1 = {0.f,0.f,0.f,0.f};
            #pragma unroll
            for (int kt = 0; kt < 3; kt++) {
                a0 = __builtin_amdgcn_mfma_f32_16x16x32_bf16(afr[kt], bfB[0][kt], a0, 0,0,0);
                a1 = __builtin_amdgcn_mfma_f32_16x16x32_bf16(afr[kt], bfB[1][kt], a1, 0,0,0);
            }
            const int ntl = g*2;
            const int j0  = (c*12 + ntl)*16 + lc;
            const float bi0 = fc1_b[j0], bi1 = fc1_b[j0 + 16];
            #pragma unroll
            for (int r = 0; r < 4; r++) {
                hid[tokr + r][ntl*16 + lc]      = f2b(gelu_exact(a0[r] + bi0));
                hid[tokr + r][(ntl+1)*16 + lc]  = f2b(gelu_exact(a1[r] + bi1));
            }
        }

        // FC2 partial: A-frags from own hid rows, 6 nt x 6 kt, accumulate acc2
        short8 af2[6];
        #pragma unroll
        for (int kt = 0; kt < 6; kt++)
            af2[kt] = *(const short8*)&hid[m0 + lc][kt*32 + 8*lr];
        #pragma unroll
        for (int nt = 0; nt < 6; nt++) {
            #pragma unroll
            for (int kt = 0; kt < 6; kt++)
                acc2[nt] = __builtin_amdgcn_mfma_f32_16x16x32_bf16(
                    af2[kt], *(const short8*)(w2f + (nt*12 + c*6 + kt)*512 + lane*8), acc2[nt], 0,0,0);
        }
    }

    // ---- final write: acc2 already holds x2 + FC2 + bias ----
    #pragma unroll
    for (int nt = 0; nt < 6; nt++) {
        const int c = nt*16 + lc;
        #pragma unroll
        for (int r = 0; r < 4; r++)
            out[toks[r] + c] = acc2[nt][r];
    }
}

extern "C" void kernel_launch(void* const* d_in, const int* in_sizes, int n_in,
                              void* d_out, int out_size, void* d_ws, size_t ws_size,
                              hipStream_t stream)
{
    const float* x      = (const float*)d_in[0];
    const float* ln1_w  = (const float*)d_in[1];
    const float* ln1_b  = (const float*)d_in[2];
    const float* qkv_w  = (const float*)d_in[3];
    const float* qkv_b  = (const float*)d_in[4];
    const float* proj_w = (const float*)d_in[5];
    const float* proj_b = (const float*)d_in[6];
    const float* ln2_w  = (const float*)d_in[7];
    const float* ln2_b  = (const float*)d_in[8];
    const float* fc1_w  = (const float*)d_in[9];
    const float* fc1_b  = (const float*)d_in[10];
    const float* fc2_w  = (const float*)d_in[11];
    const float* fc2_b  = (const float*)d_in[12];
    float* out = (float*)d_out;
    bf16* wsf  = (bf16*)d_ws;   // 216 KiB

    prep_weights<<<54, 256, 0, stream>>>(qkv_w, proj_w, fc1_w, fc2_w, wsf);
    swin_fused<<<4096, 256, 0, stream>>>(x, ln1_w, ln1_b, qkv_b, proj_b,
                                         ln2_w, ln2_b, fc1_b, fc2_b, wsf, out);
}